// Round 4
// baseline (112.082 us; speedup 1.0000x reference)
//
#include <hip/hip_runtime.h>
#include <hip/hip_bf16.h>

typedef __attribute__((ext_vector_type(4))) float f32x4;

#define N_ROWS 8192
#define B_HALF 4096
#define EXP2C 2.885390081777927f   // 2*log2(e): exp(2S) = exp2(S*EXP2C)

// ws layout (bytes)
#define WS_ZN       0                    // fp8  [8192][256] = 2 MB
#define WS_ROWACC   2097152              // float[8192]  sum_j exp(2 S_ij)
#define WS_POS      2129920              // float[8192]  raw S_pos
#define WS_DIAG     2162688              // float[8192]  exp2(S_ii*EXP2C)
#define WS_ACC      2195456              // float final accum
#define WS_CNT      2195460              // uint  block counter

__device__ __forceinline__ float fexp2(float x) {
#if __has_builtin(__builtin_amdgcn_exp2f)
    return __builtin_amdgcn_exp2f(x);
#else
    return exp2f(x);
#endif
}

__device__ __forceinline__ void async_copy16(const void* g, void* l) {
    __builtin_amdgcn_global_load_lds(
        (const __attribute__((address_space(1))) unsigned int*)g,
        (__attribute__((address_space(3))) unsigned int*)l,
        16, 0, 0);
}

// ---------------- Phase 1: L2-normalize rows, quantize to fp8 e4m3 ----------
__global__ __launch_bounds__(256) void normalize_k(
    const float* __restrict__ z_orig, const float* __restrict__ z_aug,
    unsigned char* __restrict__ zn, float* __restrict__ rowAcc,
    float* __restrict__ accum, unsigned int* __restrict__ cnt)
{
    if (blockIdx.x == 0 && threadIdx.x == 0) { *accum = 0.0f; *cnt = 0u; }
    const int row  = blockIdx.x * 4 + (threadIdx.x >> 6);
    const int lane = threadIdx.x & 63;
    if (lane == 0) rowAcc[row] = 0.0f;       // zeroed before tile_k (stream order)
    const float* src = (row < B_HALF) ? (z_aug  + (size_t)row * 256)
                                      : (z_orig + (size_t)(row - B_HALF) * 256);
    float4 v = ((const float4*)src)[lane];
    float ss = v.x*v.x + v.y*v.y + v.z*v.z + v.w*v.w;
    #pragma unroll
    for (int m = 1; m < 64; m <<= 1) ss += __shfl_xor(ss, m);
    float inv = 1.0f / fmaxf(sqrtf(ss), 1e-8f);
    int pk = 0;
    pk = __builtin_amdgcn_cvt_pk_fp8_f32(v.x * inv, v.y * inv, pk, false);
    pk = __builtin_amdgcn_cvt_pk_fp8_f32(v.z * inv, v.w * inv, pk, true);
    ((int*)(zn + (size_t)row * 256))[lane] = pk;
}

// ---------------- Phase 2: fp8 A-strip tiles ---------------------------------
// Block (jx, rb) stages A-tile (128 rows, full K=256 fp8 = 32 KB) once, then
// loops up to 4 col-tiles cb = rb+4*jx .. : B staged per sub-tile (32 KB),
// reused from As when cb==rb. XOR-16B-slot swizzle applied on the global
// address side (global_load_lds forces LDS dest = base + lane*16).
__global__ __launch_bounds__(256) void tile_k(
    const unsigned char* __restrict__ zn,
    float* __restrict__ rowAcc,         // [8192] += sum_j exp(2 S_ij)
    float* __restrict__ posv,           // [8192] raw S_pos
    float* __restrict__ diagE)          // [8192] exp2(S_ii*EXP2C)
{
    __shared__ unsigned char As[128 * 256];
    __shared__ unsigned char Bs[128 * 256];

    const int rb  = blockIdx.y;
    const int cb0 = rb + blockIdx.x * 4;
    if (cb0 > 63) return;                       // uniform early-exit
    const int nc  = min(4, 64 - cb0);

    const int t      = threadIdx.x;
    const int lane   = t & 63;
    const int w      = t >> 6;
    const int wy     = w >> 1;
    const int wx     = w & 1;
    const int lane15 = lane & 15;
    const int quad   = lane >> 4;
    const int rowBase = rb * 128;

    // staging map: shot s covers rows [s*16, s*16+16); thread t -> row s*16+(t>>4),
    // dest slot p = t&15 -> fetch logical 16B chunk q = p ^ (row&15) = p ^ (t>>4)
    const int rloc = t >> 4;                 // 0..15
    const int q16  = ((t & 15) ^ rloc) * 16;
    const int ldsW = w * 1024;

    const unsigned char* gA = zn + (size_t)rowBase * 256;
    #pragma unroll
    for (int s = 0; s < 8; ++s)
        async_copy16(gA + (size_t)(s * 16 + rloc) * 256 + q16, As + s * 4096 + ldsW);
    if (cb0 != rb) {
        const unsigned char* gB = zn + (size_t)cb0 * 128 * 256;
        #pragma unroll
        for (int s = 0; s < 8; ++s)
            async_copy16(gB + (size_t)(s * 16 + rloc) * 256 + q16, Bs + s * 4096 + ldsW);
    }

    // fragment bases: A row = wy*64 + mi*16 + lane15, B row = wx*64 + ni*16 + lane15
    const int rA = (wy * 64 + lane15) * 256;
    const int rB = (wx * 64 + lane15) * 256;

    for (int j = 0; j < nc; ++j) {
        const int cb = cb0 + j;
        const unsigned char* Bbase = (cb == rb) ? As : Bs;

        __syncthreads();                         // staging for this sub-tile done

        f32x4 acc[4][4];
        #pragma unroll
        for (int i = 0; i < 4; ++i)
            #pragma unroll
            for (int jj = 0; jj < 4; ++jj)
                acc[i][jj] = (f32x4){0.f, 0.f, 0.f, 0.f};

        #pragma unroll
        for (int ks = 0; ks < 8; ++ks) {
            // logical byte in row = ks*32 + quad*8; 16B slot swizzled by ^lane15
            const int sa = (((2 * ks + (quad >> 1)) ^ lane15) << 4) | ((quad & 1) << 3);
            long a[4], b[4];
            #pragma unroll
            for (int mi = 0; mi < 4; ++mi)
                a[mi] = *(const long*)(As + rA + mi * 4096 + sa);
            #pragma unroll
            for (int ni = 0; ni < 4; ++ni)
                b[ni] = *(const long*)(Bbase + rB + ni * 4096 + sa);
            #pragma unroll
            for (int mi = 0; mi < 4; ++mi)
                #pragma unroll
                for (int ni = 0; ni < 4; ++ni)
                    acc[mi][ni] = __builtin_amdgcn_mfma_f32_16x16x32_fp8_fp8(
                                      a[mi], b[ni], acc[mi][ni], 0, 0, 0);
        }

        __syncthreads();                         // all LDS reads done

        // prefetch next B while we do the (register-only) epilogue
        if (j + 1 < nc) {
            const unsigned char* gB = zn + (size_t)(cb + 1) * 128 * 256;
            #pragma unroll
            for (int s = 0; s < 8; ++s)
                async_copy16(gB + (size_t)(s * 16 + rloc) * 256 + q16,
                             Bs + s * 4096 + ldsW);
        }

        const int colBase = cb * 128;
        // C/D layout: m-row = quad*4 + reg, n-col = lane15 (validated r1-r3).
        const bool diagLane = (wy == wx) && ((lane15 >> 2) == quad);
        const int  rsel = lane15 & 3;
        if (cb == rb && diagLane) {
            #pragma unroll
            for (int mi = 0; mi < 4; ++mi) {
                int grow = rowBase + wy * 64 + mi * 16 + lane15;
                diagE[grow] = fexp2(acc[mi][mi][rsel] * EXP2C);
            }
        }
        if (cb == rb + 32 && diagLane) {         // positive-pair diagonal
            #pragma unroll
            for (int mi = 0; mi < 4; ++mi) {
                int grow = rowBase + wy * 64 + mi * 16 + lane15;
                float v = acc[mi][mi][rsel];
                posv[grow] = v;
                posv[grow + B_HALF] = v;
            }
        }

        // exp(2*S) in place
        #pragma unroll
        for (int mi = 0; mi < 4; ++mi)
            #pragma unroll
            for (int ni = 0; ni < 4; ++ni)
                #pragma unroll
                for (int r = 0; r < 4; ++r)
                    acc[mi][ni][r] = fexp2(acc[mi][ni][r] * EXP2C);

        // row sums (over n)
        #pragma unroll
        for (int mi = 0; mi < 4; ++mi)
            #pragma unroll
            for (int r = 0; r < 4; ++r) {
                float s = acc[mi][0][r] + acc[mi][1][r] + acc[mi][2][r] + acc[mi][3][r];
                s += __shfl_xor(s, 1);
                s += __shfl_xor(s, 2);
                s += __shfl_xor(s, 4);
                s += __shfl_xor(s, 8);
                if (lane15 == 0)
                    atomicAdd(&rowAcc[rowBase + wy * 64 + mi * 16 + quad * 4 + r], s);
            }

        // col sums (over m); off-diagonal sub-tiles only
        if (cb != rb) {
            #pragma unroll
            for (int ni = 0; ni < 4; ++ni) {
                float s = 0.0f;
                #pragma unroll
                for (int mi = 0; mi < 4; ++mi)
                    s += acc[mi][ni][0] + acc[mi][ni][1] + acc[mi][ni][2] + acc[mi][ni][3];
                s += __shfl_xor(s, 16);
                s += __shfl_xor(s, 32);
                if (quad == 0)
                    atomicAdd(&rowAcc[colBase + wx * 64 + ni * 16 + lane15], s);
            }
        }
    }
}

// ---------------- Phase 3: per-row loss + grid reduction (last block) --------
__global__ __launch_bounds__(256) void loss_k(
    const float* __restrict__ rowAcc, const float* __restrict__ posv,
    const float* __restrict__ diagE, float* __restrict__ accum,
    unsigned int* __restrict__ cnt, float* __restrict__ out)
{
    const int i = blockIdx.x * 256 + threadIdx.x;
    float s = rowAcc[i] - diagE[i];             // drop main-diagonal term
    float loss = __logf(s) - 2.0f * posv[i];    // logits = 2*S (tau = 0.5)

    #pragma unroll
    for (int m = 1; m < 64; m <<= 1) loss += __shfl_xor(loss, m);
    __shared__ float red[4];
    if ((threadIdx.x & 63) == 0) red[threadIdx.x >> 6] = loss;
    __syncthreads();
    if (threadIdx.x == 0) {
        float bs = red[0] + red[1] + red[2] + red[3];
        atomicAdd(accum, bs);
        __threadfence();
        unsigned int old = atomicAdd(cnt, 1u);
        if (old == 31u) {                       // last of 32 blocks
            __threadfence();
            float total = atomicAdd(accum, 0.0f);
            out[0] = total * (1.0f / (float)N_ROWS);
        }
    }
}

extern "C" void kernel_launch(void* const* d_in, const int* in_sizes, int n_in,
                              void* d_out, int out_size, void* d_ws, size_t ws_size,
                              hipStream_t stream) {
    const float* z_orig = (const float*)d_in[0];
    const float* z_aug  = (const float*)d_in[1];
    char* ws = (char*)d_ws;
    unsigned char* zn   = (unsigned char*)(ws + WS_ZN);
    float* rowAcc       = (float*)(ws + WS_ROWACC);
    float* posv         = (float*)(ws + WS_POS);
    float* diagE        = (float*)(ws + WS_DIAG);
    float* accum        = (float*)(ws + WS_ACC);
    unsigned int* cnt   = (unsigned int*)(ws + WS_CNT);

    normalize_k<<<N_ROWS / 4, 256, 0, stream>>>(z_orig, z_aug, zn, rowAcc, accum, cnt);
    tile_k<<<dim3(16, 64), 256, 0, stream>>>(zn, rowAcc, posv, diagE);
    loss_k<<<N_ROWS / 256, 256, 0, stream>>>(rowAcc, posv, diagE, accum, cnt,
                                             (float*)d_out);
}

// Round 5
// 108.422 us; speedup vs baseline: 1.0338x; 1.0338x over previous
//
#include <hip/hip_runtime.h>
#include <hip/hip_bf16.h>

typedef __attribute__((ext_vector_type(4))) float f32x4;
typedef __attribute__((ext_vector_type(2))) long longx2;   // 16 B LDS read

#define N_ROWS 8192
#define B_HALF 4096
#define NUT   2080          // 64*65/2 upper-triangle 128x128 tiles
#define EXP2C 2.885390081777927f   // 2*log2(e): exp(2S) = exp2(S*EXP2C)

// ws layout (bytes)
#define WS_ZN       0                    // fp8 [8192][256] PERMUTED = 2 MB
#define WS_ROWACC   2097152              // float[8192]  sum_j exp(2 S_ij)
#define WS_POS      2129920              // float[8192]  raw S_pos
#define WS_DIAG     2162688              // float[8192]  exp2(S_ii*EXP2C)
#define WS_ACC      2195456              // float final accum
#define WS_CNT      2195460              // uint  block counter

__device__ __forceinline__ float fexp2(float x) {
#if __has_builtin(__builtin_amdgcn_exp2f)
    return __builtin_amdgcn_exp2f(x);
#else
    return exp2f(x);
#endif
}

__device__ __forceinline__ void async_copy16(const void* g, void* l) {
    __builtin_amdgcn_global_load_lds(
        (const __attribute__((address_space(1))) unsigned int*)g,
        (__attribute__((address_space(3))) unsigned int*)l,
        16, 0, 0);
}

// ---------------- Phase 1: normalize -> fp8, PERMUTED row layout -------------
// Row byte order: o = 64*q + 8*ks + j  for original k = 32*ks + 8*q + j.
// This makes each MFMA lane's 8 chunk-fragments contiguous (64 B at q*64).
__global__ __launch_bounds__(256) void normalize_k(
    const float* __restrict__ z_orig, const float* __restrict__ z_aug,
    unsigned char* __restrict__ zn, float* __restrict__ rowAcc,
    float* __restrict__ accum, unsigned int* __restrict__ cnt)
{
    if (blockIdx.x == 0 && threadIdx.x == 0) { *accum = 0.0f; *cnt = 0u; }
    const int row  = blockIdx.x * 4 + (threadIdx.x >> 6);
    const int lane = threadIdx.x & 63;
    if (lane == 0) rowAcc[row] = 0.0f;       // zeroed before tile_k (stream order)
    const float* src = (row < B_HALF) ? (z_aug  + (size_t)row * 256)
                                      : (z_orig + (size_t)(row - B_HALF) * 256);
    float4 v = ((const float4*)src)[lane];
    float ss = v.x*v.x + v.y*v.y + v.z*v.z + v.w*v.w;
    #pragma unroll
    for (int m = 1; m < 64; m <<= 1) ss += __shfl_xor(ss, m);
    float inv = 1.0f / fmaxf(sqrtf(ss), 1e-8f);
    int pk = 0;
    pk = __builtin_amdgcn_cvt_pk_fp8_f32(v.x * inv, v.y * inv, pk, false);
    pk = __builtin_amdgcn_cvt_pk_fp8_f32(v.z * inv, v.w * inv, pk, true);
    // lane covers k = 4*lane..4*lane+3: ks = lane>>3, q = (lane>>1)&3, j = (lane&1)*4
    const int o4 = (((lane >> 1) & 3) << 6) | ((lane >> 3) << 3) | ((lane & 1) << 2);
    *(int*)(zn + (size_t)row * 256 + o4) = pk;
}

// ---------------- Phase 2: fp8 128x128 tiles, SINGLE barrier -----------------
// Full K=256 staged in one shot (A 32 KB + B 32 KB). Granule slot p of row r
// holds permuted-granule p ^ (r&7) (XOR applied on the global address side).
__global__ __launch_bounds__(256) void tile_k(
    const unsigned char* __restrict__ zn,
    float* __restrict__ rowAcc,         // [8192] += sum_j exp(2 S_ij)
    float* __restrict__ posv,           // [8192] raw S_pos
    float* __restrict__ diagE)          // [8192] exp2(S_ii*EXP2C)
{
    __shared__ unsigned char As[128 * 256];
    __shared__ unsigned char Bs[128 * 256];

    const int bid = blockIdx.x;
    // decode upper-triangular (rb, cb), cb >= rb; C(r) = r*(129-r)/2
    int rb = (int)((129.0f - sqrtf(16641.0f - 8.0f * (float)bid)) * 0.5f);
    rb = rb < 0 ? 0 : (rb > 63 ? 63 : rb);
    while ((rb + 1) * (129 - (rb + 1)) / 2 <= bid) ++rb;
    while (rb * (129 - rb) / 2 > bid) --rb;
    const int cb = rb + (bid - rb * (129 - rb) / 2);

    const int t      = threadIdx.x;
    const int lane   = t & 63;
    const int w      = t >> 6;
    const int wy     = w >> 1;
    const int wx     = w & 1;
    const int lane15 = lane & 15;
    const int quad   = lane >> 4;
    const int rowBase = rb * 128;
    const int colBase = cb * 128;

    // staging: shot s covers rows [s*16, s*16+16); thread t -> row s*16+(t>>4),
    // dest slot p = t&15; fetch global granule p ^ (row&7)
    const int rloc = t >> 4;                 // 0..15
    const int q16  = (((t & 15) ^ (rloc & 7)) << 4);
    const int ldsW = w * 1024;

    const unsigned char* gA = zn + (size_t)rowBase * 256;
    #pragma unroll
    for (int s = 0; s < 8; ++s)
        async_copy16(gA + (size_t)(s * 16 + rloc) * 256 + q16, As + s * 4096 + ldsW);
    if (cb != rb) {
        const unsigned char* gB = zn + (size_t)colBase * 256;
        #pragma unroll
        for (int s = 0; s < 8; ++s)
            async_copy16(gB + (size_t)(s * 16 + rloc) * 256 + q16, Bs + s * 4096 + ldsW);
    }
    const unsigned char* Bbase = (cb == rb) ? As : Bs;

    f32x4 acc[4][4];
    #pragma unroll
    for (int i = 0; i < 4; ++i)
        #pragma unroll
        for (int j = 0; j < 4; ++j)
            acc[i][j] = (f32x4){0.f, 0.f, 0.f, 0.f};

    const int h  = lane15 & 7;
    const int rA = (wy * 64 + lane15) * 256;
    const int rB = (wx * 64 + lane15) * 256;

    __syncthreads();                         // THE one barrier: staging complete

    #pragma unroll
    for (int t4 = 0; t4 < 4; ++t4) {
        // granule g = 4*quad + t4 (16 B = frags of chunks 2*t4, 2*t4+1)
        const int off = (((4 * quad + t4) ^ h) << 4);
        longx2 a[4], b[4];
        #pragma unroll
        for (int mi = 0; mi < 4; ++mi)
            a[mi] = *(const longx2*)(As + rA + mi * 4096 + off);
        #pragma unroll
        for (int ni = 0; ni < 4; ++ni)
            b[ni] = *(const longx2*)(Bbase + rB + ni * 4096 + off);
        #pragma unroll
        for (int mi = 0; mi < 4; ++mi)
            #pragma unroll
            for (int ni = 0; ni < 4; ++ni)
                acc[mi][ni] = __builtin_amdgcn_mfma_f32_16x16x32_fp8_fp8(
                                  a[mi].x, b[ni].x, acc[mi][ni], 0, 0, 0);
        #pragma unroll
        for (int mi = 0; mi < 4; ++mi)
            #pragma unroll
            for (int ni = 0; ni < 4; ++ni)
                acc[mi][ni] = __builtin_amdgcn_mfma_f32_16x16x32_fp8_fp8(
                                  a[mi].y, b[ni].y, acc[mi][ni], 0, 0, 0);
    }

    // C/D layout: m-row = quad*4 + reg, n-col = lane15 (validated r1-r4).
    const bool diagLane = (wy == wx) && ((lane15 >> 2) == quad);
    const int  rsel = lane15 & 3;
    if (cb == rb && diagLane) {
        #pragma unroll
        for (int mi = 0; mi < 4; ++mi) {
            int grow = rowBase + wy * 64 + mi * 16 + lane15;
            diagE[grow] = fexp2(acc[mi][mi][rsel] * EXP2C);
        }
    }
    if (cb == rb + 32 && diagLane) {         // positive-pair diagonal
        #pragma unroll
        for (int mi = 0; mi < 4; ++mi) {
            int grow = rowBase + wy * 64 + mi * 16 + lane15;
            float v = acc[mi][mi][rsel];
            posv[grow] = v;
            posv[grow + B_HALF] = v;
        }
    }

    // exp(2*S) in place
    #pragma unroll
    for (int mi = 0; mi < 4; ++mi)
        #pragma unroll
        for (int ni = 0; ni < 4; ++ni)
            #pragma unroll
            for (int r = 0; r < 4; ++r)
                acc[mi][ni][r] = fexp2(acc[mi][ni][r] * EXP2C);

    // row sums (over n): global atomics, no barrier
    #pragma unroll
    for (int mi = 0; mi < 4; ++mi)
        #pragma unroll
        for (int r = 0; r < 4; ++r) {
            float s = acc[mi][0][r] + acc[mi][1][r] + acc[mi][2][r] + acc[mi][3][r];
            s += __shfl_xor(s, 1);
            s += __shfl_xor(s, 2);
            s += __shfl_xor(s, 4);
            s += __shfl_xor(s, 8);
            if (lane15 == 0)
                atomicAdd(&rowAcc[rowBase + wy * 64 + mi * 16 + quad * 4 + r], s);
        }

    // col sums (over m); off-diagonal tiles only
    if (cb != rb) {
        #pragma unroll
        for (int ni = 0; ni < 4; ++ni) {
            float s = 0.0f;
            #pragma unroll
            for (int mi = 0; mi < 4; ++mi)
                s += acc[mi][ni][0] + acc[mi][ni][1] + acc[mi][ni][2] + acc[mi][ni][3];
            s += __shfl_xor(s, 16);
            s += __shfl_xor(s, 32);
            if (quad == 0)
                atomicAdd(&rowAcc[colBase + wx * 64 + ni * 16 + lane15], s);
        }
    }
}

// ---------------- Phase 3: per-row loss + grid reduction (last block) --------
__global__ __launch_bounds__(256) void loss_k(
    const float* __restrict__ rowAcc, const float* __restrict__ posv,
    const float* __restrict__ diagE, float* __restrict__ accum,
    unsigned int* __restrict__ cnt, float* __restrict__ out)
{
    const int i = blockIdx.x * 256 + threadIdx.x;
    float s = rowAcc[i] - diagE[i];             // drop main-diagonal term
    float loss = __logf(s) - 2.0f * posv[i];    // logits = 2*S (tau = 0.5)

    #pragma unroll
    for (int m = 1; m < 64; m <<= 1) loss += __shfl_xor(loss, m);
    __shared__ float red[4];
    if ((threadIdx.x & 63) == 0) red[threadIdx.x >> 6] = loss;
    __syncthreads();
    if (threadIdx.x == 0) {
        float bs = red[0] + red[1] + red[2] + red[3];
        atomicAdd(accum, bs);
        __threadfence();
        unsigned int old = atomicAdd(cnt, 1u);
        if (old == 31u) {                       // last of 32 blocks
            __threadfence();
            float total = atomicAdd(accum, 0.0f);
            out[0] = total * (1.0f / (float)N_ROWS);
        }
    }
}

extern "C" void kernel_launch(void* const* d_in, const int* in_sizes, int n_in,
                              void* d_out, int out_size, void* d_ws, size_t ws_size,
                              hipStream_t stream) {
    const float* z_orig = (const float*)d_in[0];
    const float* z_aug  = (const float*)d_in[1];
    char* ws = (char*)d_ws;
    unsigned char* zn   = (unsigned char*)(ws + WS_ZN);
    float* rowAcc       = (float*)(ws + WS_ROWACC);
    float* posv         = (float*)(ws + WS_POS);
    float* diagE        = (float*)(ws + WS_DIAG);
    float* accum        = (float*)(ws + WS_ACC);
    unsigned int* cnt   = (unsigned int*)(ws + WS_CNT);

    normalize_k<<<N_ROWS / 4, 256, 0, stream>>>(z_orig, z_aug, zn, rowAcc, accum, cnt);
    tile_k<<<NUT, 256, 0, stream>>>(zn, rowAcc, posv, diagE);
    loss_k<<<N_ROWS / 256, 256, 0, stream>>>(rowAcc, posv, diagE, accum, cnt,
                                             (float*)d_out);
}

// Round 6
// 100.664 us; speedup vs baseline: 1.1134x; 1.0771x over previous
//
#include <hip/hip_runtime.h>
#include <hip/hip_bf16.h>

typedef __attribute__((ext_vector_type(4))) float f32x4;
typedef __attribute__((ext_vector_type(2))) long longx2;   // 16 B global load

#define N_ROWS 8192
#define B_HALF 4096
#define NUT   2080          // 64*65/2 upper-triangle 128x128 tiles
#define EXP2C 2.885390081777927f   // 2*log2(e): exp(2S) = exp2(S*EXP2C)

// ws layout (bytes)
#define WS_ZN       0                    // fp8 [8192/16][4][16][4][16B] frag-major = 2 MB
#define WS_ROWACC   2097152              // float[8192]  sum_j exp(2 S_ij)
#define WS_POS      2129920              // float[8192]  raw S_pos
#define WS_DIAG     2162688              // float[8192]  exp2(S_ii*EXP2C)
#define WS_ACC      2195456              // float final accum
#define WS_CNT      2195460              // uint  block counter

__device__ __forceinline__ float fexp2(float x) {
#if __has_builtin(__builtin_amdgcn_exp2f)
    return __builtin_amdgcn_exp2f(x);
#else
    return exp2f(x);
#endif
}

// ---------------- Phase 1: normalize -> fp8, FRAGMENT-MAJOR layout -----------
// For original element k of row r:  ks=k>>5 (K-chunk), q=(k>>3)&3 (MFMA quad),
// j=k&7, t4=ks>>1, half=ks&1.  Stored at:
//   addr = (r>>4)*4096 + t4*1024 + (r&15)*64 + q*16 + half*8 + j
// so the 16B granule (r,q,t4) = [chunk 2*t4 frag | chunk 2*t4+1 frag] and a
// wave's fragment load (fixed r16,t4; lanes = m + 16*q) is contiguous 1 KB.
__global__ __launch_bounds__(256) void normalize_k(
    const float* __restrict__ z_orig, const float* __restrict__ z_aug,
    unsigned char* __restrict__ zn, float* __restrict__ rowAcc,
    float* __restrict__ accum, unsigned int* __restrict__ cnt)
{
    if (blockIdx.x == 0 && threadIdx.x == 0) { *accum = 0.0f; *cnt = 0u; }
    const int row  = blockIdx.x * 4 + (threadIdx.x >> 6);
    const int lane = threadIdx.x & 63;
    if (lane == 0) rowAcc[row] = 0.0f;       // zeroed before tile_k (stream order)
    const float* src = (row < B_HALF) ? (z_aug  + (size_t)row * 256)
                                      : (z_orig + (size_t)(row - B_HALF) * 256);
    float4 v = ((const float4*)src)[lane];
    float ss = v.x*v.x + v.y*v.y + v.z*v.z + v.w*v.w;
    #pragma unroll
    for (int m = 1; m < 64; m <<= 1) ss += __shfl_xor(ss, m);
    float inv = 1.0f / fmaxf(sqrtf(ss), 1e-8f);
    int pk = 0;
    pk = __builtin_amdgcn_cvt_pk_fp8_f32(v.x * inv, v.y * inv, pk, false);
    pk = __builtin_amdgcn_cvt_pk_fp8_f32(v.z * inv, v.w * inv, pk, true);
    // lane covers k = 4*lane .. 4*lane+3 (all share ks,q,t4,half; j = (lane&1)*4)
    const int addr = ((row >> 4) << 12) | ((lane >> 4) << 10) | ((row & 15) << 6)
                   | (((lane >> 1) & 3) << 4) | (((lane >> 3) & 1) << 3)
                   | ((lane & 1) << 2);
    *(int*)(zn + addr) = pk;
}

// ---------------- Phase 2: LDS-free fp8 128x128 tiles ------------------------
// All operands loaded global->VGPR as coalesced 1KB dwordx4 instructions from
// the fragment-major zn (L2/L3-resident). No LDS, no barriers; 2080 fully
// independent blocks.
__global__ __launch_bounds__(256, 3) void tile_k(
    const unsigned char* __restrict__ zn,
    float* __restrict__ rowAcc,         // [8192] += sum_j exp(2 S_ij)
    float* __restrict__ posv,           // [8192] raw S_pos
    float* __restrict__ diagE)          // [8192] exp2(S_ii*EXP2C)
{
    const int bid = blockIdx.x;
    // decode upper-triangular (rb, cb), cb >= rb; C(r) = r*(129-r)/2
    int rb = (int)((129.0f - sqrtf(16641.0f - 8.0f * (float)bid)) * 0.5f);
    rb = rb < 0 ? 0 : (rb > 63 ? 63 : rb);
    while ((rb + 1) * (129 - (rb + 1)) / 2 <= bid) ++rb;
    while (rb * (129 - rb) / 2 > bid) --rb;
    const int cb = rb + (bid - rb * (129 - rb) / 2);

    const int t      = threadIdx.x;
    const int lane   = t & 63;
    const int w      = t >> 6;
    const int wy     = w >> 1;
    const int wx     = w & 1;
    const int lane15 = lane & 15;
    const int quad   = lane >> 4;
    const int rowBase = rb * 128;
    const int colBase = cb * 128;

    // fragment base: group r16 = rb*8 + wy*4 + mi  (A) / cb*8 + wx*4 + ni (B)
    const int laneOff = lane15 * 64 + quad * 16;
    const unsigned char* gA = zn + (size_t)(rb * 8 + wy * 4) * 4096 + laneOff;
    const unsigned char* gB = zn + (size_t)(cb * 8 + wx * 4) * 4096 + laneOff;

    f32x4 acc[4][4];
    #pragma unroll
    for (int i = 0; i < 4; ++i)
        #pragma unroll
        for (int j = 0; j < 4; ++j)
            acc[i][j] = (f32x4){0.f, 0.f, 0.f, 0.f};

    #pragma unroll 1
    for (int t4 = 0; t4 < 4; ++t4) {
        longx2 a[4], b[4];
        #pragma unroll
        for (int mi = 0; mi < 4; ++mi)
            a[mi] = *(const longx2*)(gA + mi * 4096 + t4 * 1024);
        #pragma unroll
        for (int ni = 0; ni < 4; ++ni)
            b[ni] = *(const longx2*)(gB + ni * 4096 + t4 * 1024);
        #pragma unroll
        for (int mi = 0; mi < 4; ++mi)
            #pragma unroll
            for (int ni = 0; ni < 4; ++ni)
                acc[mi][ni] = __builtin_amdgcn_mfma_f32_16x16x32_fp8_fp8(
                                  a[mi].x, b[ni].x, acc[mi][ni], 0, 0, 0);
        #pragma unroll
        for (int mi = 0; mi < 4; ++mi)
            #pragma unroll
            for (int ni = 0; ni < 4; ++ni)
                acc[mi][ni] = __builtin_amdgcn_mfma_f32_16x16x32_fp8_fp8(
                                  a[mi].y, b[ni].y, acc[mi][ni], 0, 0, 0);
    }

    // C/D layout: m-row = quad*4 + reg, n-col = lane15 (validated r1-r5).
    const bool diagLane = (wy == wx) && ((lane15 >> 2) == quad);
    const int  rsel = lane15 & 3;
    if (cb == rb && diagLane) {
        #pragma unroll
        for (int mi = 0; mi < 4; ++mi) {
            int grow = rowBase + wy * 64 + mi * 16 + lane15;
            diagE[grow] = fexp2(acc[mi][mi][rsel] * EXP2C);
        }
    }
    if (cb == rb + 32 && diagLane) {         // positive-pair diagonal
        #pragma unroll
        for (int mi = 0; mi < 4; ++mi) {
            int grow = rowBase + wy * 64 + mi * 16 + lane15;
            float v = acc[mi][mi][rsel];
            posv[grow] = v;
            posv[grow + B_HALF] = v;
        }
    }

    // exp(2*S) in place
    #pragma unroll
    for (int mi = 0; mi < 4; ++mi)
        #pragma unroll
        for (int ni = 0; ni < 4; ++ni)
            #pragma unroll
            for (int r = 0; r < 4; ++r)
                acc[mi][ni][r] = fexp2(acc[mi][ni][r] * EXP2C);

    // row sums (over n): global atomics, no barrier
    #pragma unroll
    for (int mi = 0; mi < 4; ++mi)
        #pragma unroll
        for (int r = 0; r < 4; ++r) {
            float s = acc[mi][0][r] + acc[mi][1][r] + acc[mi][2][r] + acc[mi][3][r];
            s += __shfl_xor(s, 1);
            s += __shfl_xor(s, 2);
            s += __shfl_xor(s, 4);
            s += __shfl_xor(s, 8);
            if (lane15 == 0)
                atomicAdd(&rowAcc[rowBase + wy * 64 + mi * 16 + quad * 4 + r], s);
        }

    // col sums (over m); off-diagonal tiles only
    if (cb != rb) {
        #pragma unroll
        for (int ni = 0; ni < 4; ++ni) {
            float s = 0.0f;
            #pragma unroll
            for (int mi = 0; mi < 4; ++mi)
                s += acc[mi][ni][0] + acc[mi][ni][1] + acc[mi][ni][2] + acc[mi][ni][3];
            s += __shfl_xor(s, 16);
            s += __shfl_xor(s, 32);
            if (quad == 0)
                atomicAdd(&rowAcc[colBase + wx * 64 + ni * 16 + lane15], s);
        }
    }
}

// ---------------- Phase 3: per-row loss + grid reduction (last block) --------
__global__ __launch_bounds__(256) void loss_k(
    const float* __restrict__ rowAcc, const float* __restrict__ posv,
    const float* __restrict__ diagE, float* __restrict__ accum,
    unsigned int* __restrict__ cnt, float* __restrict__ out)
{
    const int i = blockIdx.x * 256 + threadIdx.x;
    float s = rowAcc[i] - diagE[i];             // drop main-diagonal term
    float loss = __logf(s) - 2.0f * posv[i];    // logits = 2*S (tau = 0.5)

    #pragma unroll
    for (int m = 1; m < 64; m <<= 1) loss += __shfl_xor(loss, m);
    __shared__ float red[4];
    if ((threadIdx.x & 63) == 0) red[threadIdx.x >> 6] = loss;
    __syncthreads();
    if (threadIdx.x == 0) {
        float bs = red[0] + red[1] + red[2] + red[3];
        atomicAdd(accum, bs);
        __threadfence();
        unsigned int old = atomicAdd(cnt, 1u);
        if (old == 31u) {                       // last of 32 blocks
            __threadfence();
            float total = atomicAdd(accum, 0.0f);
            out[0] = total * (1.0f / (float)N_ROWS);
        }
    }
}

extern "C" void kernel_launch(void* const* d_in, const int* in_sizes, int n_in,
                              void* d_out, int out_size, void* d_ws, size_t ws_size,
                              hipStream_t stream) {
    const float* z_orig = (const float*)d_in[0];
    const float* z_aug  = (const float*)d_in[1];
    char* ws = (char*)d_ws;
    unsigned char* zn   = (unsigned char*)(ws + WS_ZN);
    float* rowAcc       = (float*)(ws + WS_ROWACC);
    float* posv         = (float*)(ws + WS_POS);
    float* diagE        = (float*)(ws + WS_DIAG);
    float* accum        = (float*)(ws + WS_ACC);
    unsigned int* cnt   = (unsigned int*)(ws + WS_CNT);

    normalize_k<<<N_ROWS / 4, 256, 0, stream>>>(z_orig, z_aug, zn, rowAcc, accum, cnt);
    tile_k<<<NUT, 256, 0, stream>>>(zn, rowAcc, posv, diagE);
    loss_k<<<N_ROWS / 256, 256, 0, stream>>>(rowAcc, posv, diagE, accum, cnt,
                                             (float*)d_out);
}